// Round 1
// baseline (747.732 us; speedup 1.0000x reference)
//
#include <hip/hip_runtime.h>
#include <math.h>

namespace {
constexpr int S = 192;
constexpr long long S2 = (long long)S * S;
constexpr long long S3 = (long long)S * S2;
constexpr int B = 4;
constexpr int K = 11;
constexpr int R = 5;       // radius
constexpr int DCH = 48;    // d-chunk size in pass 3 (more blocks for occupancy)
constexpr float C1f = 1e-4f;
constexpr float C2f = 9e-4f;

struct GaussW { float g[K]; };

__global__ void k_init(double* acc) { *acc = 0.0; }

__global__ void k_final(const double* __restrict__ acc, float* __restrict__ out) {
  out[0] = (float)(acc[0] / (double)(B * S3));
}

// ---- Pass 1: blur along W (contiguous axis) + form the 5 product fields ----
// grid.x = number of rows in this launch; block = 192 threads (one per w)
__global__ __launch_bounds__(192) void k_blurW(
    const float* __restrict__ gt, const float* __restrict__ pr,
    float* __restrict__ buf, long long in_base, long long fstride, GaussW W) {
  __shared__ float as[S], bs[S];
  long long row = blockIdx.x;
  int w = threadIdx.x;
  long long in_off = in_base + row * S + w;
  as[w] = gt[in_off];
  bs[w] = pr[in_off];
  __syncthreads();
  float s0 = 0.f, s1 = 0.f, s2 = 0.f, s3 = 0.f, s4 = 0.f;
#pragma unroll
  for (int t = 0; t < K; ++t) {
    int wi = w + t - R;
    if (wi >= 0 && wi < S) {       // zero padding: skip OOB taps
      float a = as[wi], b = bs[wi], wt = W.g[t];
      s0 = fmaf(wt, a, s0);
      s1 = fmaf(wt, b, s1);
      s2 = fmaf(wt * a, a, s2);
      s3 = fmaf(wt * b, b, s3);
      s4 = fmaf(wt * a, b, s4);
    }
  }
  long long o = row * S + w;
  buf[o] = s0;
  buf[fstride + o] = s1;
  buf[2 * fstride + o] = s2;
  buf[3 * fstride + o] = s3;
  buf[4 * fstride + o] = s4;
}

// ---- Pass 2: blur along H, IN PLACE, sliding register ring ----
// grid = (d=S, n, f=5); block = 192 threads (w). Each element of the column
// is loaded into the ring at step h-5 and overwritten at step h -> race-free.
__global__ __launch_bounds__(192) void k_blurH(
    float* __restrict__ buf, long long fstride, GaussW W) {
  int w = threadIdx.x;
  int d = blockIdx.x;
  long long n = blockIdx.y;
  long long f = blockIdx.z;
  float* p = buf + f * fstride + n * S3 + (long long)d * S2 + w;
  float win[K];
#pragma unroll
  for (int i = 0; i < K; ++i) win[i] = 0.f;
#pragma unroll
  for (int j = 0; j < R; ++j) win[R + j] = p[(long long)j * S];  // x[0..4]
  for (int h = 0; h < S; ++h) {
    win[K - 1] = (h + R < S) ? p[(long long)(h + R) * S] : 0.f;
    float s = 0.f;
#pragma unroll
    for (int i = 0; i < K; ++i) s = fmaf(W.g[i], win[i], s);
    p[(long long)h * S] = s;
#pragma unroll
    for (int i = 0; i < K - 1; ++i) win[i] = win[i + 1];
  }
}

// ---- Pass 3: blur along D + SSIM + mean-reduce, fused ----
// grid = (h=S, n, c=S/DCH); block = 192 threads (w). 5 register rings.
__global__ __launch_bounds__(192) void k_blurD_ssim(
    const float* __restrict__ buf, long long fstride,
    double* __restrict__ acc, GaussW W) {
  int w = threadIdx.x;
  int h = blockIdx.x;
  long long n = blockIdx.y;
  int d0 = (int)blockIdx.z * DCH;
  const float* p = buf + n * S3 + (long long)h * S + w;
  float win[5][K];
#pragma unroll
  for (int f = 0; f < 5; ++f)
#pragma unroll
    for (int i = 0; i < K; ++i) win[f][i] = 0.f;
  // preload win[f][i] = x[d0-5+i], i = 0..K-2  (d0+4 < S always)
#pragma unroll
  for (int i = 0; i < K - 1; ++i) {
    int d = d0 - R + i;
    if (d >= 0) {
#pragma unroll
      for (int f = 0; f < 5; ++f)
        win[f][i] = p[f * fstride + (long long)d * S2];
    }
  }
  double lsum = 0.0;
  for (int d = d0; d < d0 + DCH; ++d) {
    int dl = d + R;
#pragma unroll
    for (int f = 0; f < 5; ++f)
      win[f][K - 1] = (dl < S) ? p[f * fstride + (long long)dl * S2] : 0.f;
    float m[5];
#pragma unroll
    for (int f = 0; f < 5; ++f) {
      float s = 0.f;
#pragma unroll
      for (int i = 0; i < K; ++i) s = fmaf(W.g[i], win[f][i], s);
      m[f] = s;
    }
    float mux = m[0], muy = m[1], bxx = m[2], byy = m[3], bxy = m[4];
    float mux2 = mux * mux, muy2 = muy * muy, muxy = mux * muy;
    float sx = bxx - mux2, sy = byy - muy2, sxy = bxy - muxy;
    float num = (2.f * muxy + C1f) * (2.f * sxy + C2f);
    float den = (mux2 + muy2 + C1f) * (sx + sy + C2f);
    lsum += (double)(1.f - num / den);
#pragma unroll
    for (int f = 0; f < 5; ++f)
#pragma unroll
      for (int i = 0; i < K - 1; ++i) win[f][i] = win[f][i + 1];
  }
  // block reduction: wave shuffle -> LDS -> one atomic per block
  double v = lsum;
#pragma unroll
  for (int o = 32; o > 0; o >>= 1) v += __shfl_down(v, o, 64);
  __shared__ double wsum[3];
  int lane = threadIdx.x & 63, wv = threadIdx.x >> 6;
  if (lane == 0) wsum[wv] = v;
  __syncthreads();
  if (threadIdx.x == 0) atomicAdd(acc, wsum[0] + wsum[1] + wsum[2]);
}

}  // namespace

extern "C" void kernel_launch(void* const* d_in, const int* in_sizes, int n_in,
                              void* d_out, int out_size, void* d_ws, size_t ws_size,
                              hipStream_t stream) {
  (void)in_sizes; (void)n_in; (void)out_size;
  const float* gt = (const float*)d_in[0];
  const float* pr = (const float*)d_in[1];
  float* out = (float*)d_out;
  double* acc = (double*)d_ws;
  float* buf = (float*)((char*)d_ws + 256);

  GaussW W;
  {
    double gg[K], sum = 0.0;
    for (int i = 0; i < K; ++i) {
      double x = (double)(i - K / 2);
      gg[i] = exp(-(x * x) / (2.0 * 1.5 * 1.5)) / (sqrt(2.0 * M_PI) * 1.5);
      sum += gg[i];
    }
    for (int i = 0; i < K; ++i) W.g[i] = (float)(gg[i] / sum);
  }

  const size_t need_full = 256 + 5ull * B * S3 * 4;  // ~566 MB
  k_init<<<dim3(1), dim3(1), 0, stream>>>(acc);
  if (ws_size >= need_full) {
    // whole-volume path: 3 big dispatches
    k_blurW<<<dim3(B * S * S), dim3(S), 0, stream>>>(gt, pr, buf, 0, (long long)B * S3, W);
    k_blurH<<<dim3(S, B, 5), dim3(S), 0, stream>>>(buf, (long long)B * S3, W);
    k_blurD_ssim<<<dim3(S, B, S / DCH), dim3(S), 0, stream>>>(buf, (long long)B * S3, acc, W);
  } else {
    // per-batch path: 142 MB scratch
    for (int n = 0; n < B; ++n) {
      k_blurW<<<dim3(S * S), dim3(S), 0, stream>>>(gt, pr, buf, (long long)n * S3, S3, W);
      k_blurH<<<dim3(S, 1, 5), dim3(S), 0, stream>>>(buf, S3, W);
      k_blurD_ssim<<<dim3(S, 1, S / DCH), dim3(S), 0, stream>>>(buf, S3, acc, W);
    }
  }
  k_final<<<dim3(1), dim3(1), 0, stream>>>(acc, out);
}

// Round 2
// 659.533 us; speedup vs baseline: 1.1337x; 1.1337x over previous
//
#include <hip/hip_runtime.h>
#include <hip/hip_fp16.h>
#include <math.h>

namespace {
constexpr int S = 192;
constexpr long long S2 = (long long)S * S;
constexpr long long S3 = (long long)S * S2;
constexpr int B = 4;
constexpr int K = 11;
constexpr int R = 5;       // radius
constexpr int DCH = 48;    // d-chunk in pass 2
constexpr float C1f = 1e-4f;
constexpr float C2f = 9e-4f;

struct GaussW { float g[K]; };

__global__ void k_init(double* acc) { *acc = 0.0; }

__global__ void k_final(const double* __restrict__ acc, float* __restrict__ out) {
  out[0] = (float)(acc[0] / (double)(B * S3));
}

// ---- Kernel A: fused W-blur + H-blur of the 5 product fields ----
// grid = (dz = S, n = batches-in-launch); block = 192 threads (w).
// Register ring along h (5 fields x 11 taps); per h-row: stage raw row into
// interleaved float2 LDS (1 ds_write_b64), W-blur products (11 ds_read_b64),
// H-ring accumulate, store 5 fp16 fields. Reads gt/pr exactly once.
__global__ __launch_bounds__(192) void k_blurWH(
    const float* __restrict__ gt, const float* __restrict__ pr,
    __half* __restrict__ buf, long long in_base, long long fstride, GaussW W) {
  // row[8+w] holds (gt,pr) for w=0..191; [0..7] and [200..207] are zero pads
  __shared__ float2 row[208];
  const int w = threadIdx.x;
  const int dz = blockIdx.x;
  const long long n = blockIdx.y;
  const float* pg = gt + in_base + ((n * S + dz) * (long long)S) * S;
  const float* pp = pr + in_base + ((n * S + dz) * (long long)S) * S;
  __half* po = buf + ((n * S + dz) * (long long)S) * S + w;  // + f*fstride + h*S

  if (w < 8) {
    row[w] = make_float2(0.f, 0.f);
    row[200 + w] = make_float2(0.f, 0.f);
  }

  float win[5][K];
#pragma unroll
  for (int f = 0; f < 5; ++f)
#pragma unroll
    for (int i = 0; i < K; ++i) win[f][i] = 0.f;

  // stage source row hs, W-blur the 5 products for this thread's w
  auto stage_blur = [&](int hs, float out5[5]) {
    if (hs < S) {
      float a = pg[(long long)hs * S + w];
      float b = pp[(long long)hs * S + w];
      row[8 + w] = make_float2(a, b);
    }
    __syncthreads();
    float s0 = 0.f, s1 = 0.f, s2 = 0.f, s3 = 0.f, s4 = 0.f;
    if (hs < S) {
#pragma unroll
      for (int i = 0; i < K; ++i) {
        float2 ab = row[w + 3 + i];  // w - 5 + i + 8
        float t = W.g[i] * ab.x;
        float u = W.g[i] * ab.y;
        s0 += t;
        s1 += u;
        s2 = fmaf(t, ab.x, s2);
        s3 = fmaf(u, ab.y, s3);
        s4 = fmaf(t, ab.y, s4);
      }
    }
    __syncthreads();  // protect row[] before next stage overwrites
    out5[0] = s0; out5[1] = s1; out5[2] = s2; out5[3] = s3; out5[4] = s4;
  };

  // preload source rows 0..4 into ring slots 5..9
#pragma unroll
  for (int j = 0; j < R; ++j) {
    float o[5];
    stage_blur(j, o);
#pragma unroll
    for (int f = 0; f < 5; ++f) win[f][R + j] = o[f];
  }

  for (int h = 0; h < S; ++h) {
    float o[5];
    stage_blur(h + R, o);
#pragma unroll
    for (int f = 0; f < 5; ++f) win[f][K - 1] = o[f];
#pragma unroll
    for (int f = 0; f < 5; ++f) {
      float s = 0.f;
#pragma unroll
      for (int i = 0; i < K; ++i) s = fmaf(W.g[i], win[f][i], s);
      po[f * fstride + (long long)h * S] = __float2half(s);
    }
#pragma unroll
    for (int f = 0; f < 5; ++f)
#pragma unroll
      for (int i = 0; i < K - 1; ++i) win[f][i] = win[f][i + 1];
  }
}

// ---- Kernel B: D-blur + SSIM + mean-reduce, fused (fp16 in) ----
// grid = (h = S, n, c = S/DCH); block = 192 threads (w). 5 register rings.
__global__ __launch_bounds__(192) void k_blurD_ssim(
    const __half* __restrict__ buf, long long fstride,
    double* __restrict__ acc, GaussW W) {
  const int w = threadIdx.x;
  const int h = blockIdx.x;
  const long long n = blockIdx.y;
  const int d0 = (int)blockIdx.z * DCH;
  const __half* p = buf + n * S3 + (long long)h * S + w;
  float win[5][K];
#pragma unroll
  for (int f = 0; f < 5; ++f)
#pragma unroll
    for (int i = 0; i < K; ++i) win[f][i] = 0.f;
#pragma unroll
  for (int i = 0; i < K - 1; ++i) {
    int d = d0 - R + i;
    if (d >= 0) {
#pragma unroll
      for (int f = 0; f < 5; ++f)
        win[f][i] = __half2float(p[f * fstride + (long long)d * S2]);
    }
  }
  double lsum = 0.0;
  for (int d = d0; d < d0 + DCH; ++d) {
    int dl = d + R;
#pragma unroll
    for (int f = 0; f < 5; ++f)
      win[f][K - 1] = (dl < S) ? __half2float(p[f * fstride + (long long)dl * S2]) : 0.f;
    float m[5];
#pragma unroll
    for (int f = 0; f < 5; ++f) {
      float s = 0.f;
#pragma unroll
      for (int i = 0; i < K; ++i) s = fmaf(W.g[i], win[f][i], s);
      m[f] = s;
    }
    float mux = m[0], muy = m[1], bxx = m[2], byy = m[3], bxy = m[4];
    float mux2 = mux * mux, muy2 = muy * muy, muxy = mux * muy;
    float sx = bxx - mux2, sy = byy - muy2, sxy = bxy - muxy;
    float num = (2.f * muxy + C1f) * (2.f * sxy + C2f);
    float den = (mux2 + muy2 + C1f) * (sx + sy + C2f);
    lsum += (double)(1.f - num / den);
#pragma unroll
    for (int f = 0; f < 5; ++f)
#pragma unroll
      for (int i = 0; i < K - 1; ++i) win[f][i] = win[f][i + 1];
  }
  double v = lsum;
#pragma unroll
  for (int o = 32; o > 0; o >>= 1) v += __shfl_down(v, o, 64);
  __shared__ double wsum[3];
  int lane = threadIdx.x & 63, wv = threadIdx.x >> 6;
  if (lane == 0) wsum[wv] = v;
  __syncthreads();
  if (threadIdx.x == 0) atomicAdd(acc, wsum[0] + wsum[1] + wsum[2]);
}

}  // namespace

extern "C" void kernel_launch(void* const* d_in, const int* in_sizes, int n_in,
                              void* d_out, int out_size, void* d_ws, size_t ws_size,
                              hipStream_t stream) {
  (void)in_sizes; (void)n_in; (void)out_size;
  const float* gt = (const float*)d_in[0];
  const float* pr = (const float*)d_in[1];
  float* out = (float*)d_out;
  double* acc = (double*)d_ws;
  __half* buf = (__half*)((char*)d_ws + 256);

  GaussW W;
  {
    double gg[K], sum = 0.0;
    for (int i = 0; i < K; ++i) {
      double x = (double)(i - K / 2);
      gg[i] = exp(-(x * x) / (2.0 * 1.5 * 1.5)) / (sqrt(2.0 * M_PI) * 1.5);
      sum += gg[i];
    }
    for (int i = 0; i < K; ++i) W.g[i] = (float)(gg[i] / sum);
  }

  const size_t need_full = 256 + 5ull * B * S3 * sizeof(__half);  // ~283 MB
  const size_t need_pair = 256 + 5ull * 2 * S3 * sizeof(__half);  // ~142 MB

  k_init<<<dim3(1), dim3(1), 0, stream>>>(acc);
  if (ws_size >= need_full) {
    k_blurWH<<<dim3(S, B), dim3(S), 0, stream>>>(gt, pr, buf, 0, (long long)B * S3, W);
    k_blurD_ssim<<<dim3(S, B, S / DCH), dim3(S), 0, stream>>>(buf, (long long)B * S3, acc, W);
  } else if (ws_size >= need_pair) {
    for (int g = 0; g < B; g += 2) {
      k_blurWH<<<dim3(S, 2), dim3(S), 0, stream>>>(gt, pr, buf, (long long)g * S3,
                                                   (long long)2 * S3, W);
      k_blurD_ssim<<<dim3(S, 2, S / DCH), dim3(S), 0, stream>>>(buf, (long long)2 * S3, acc, W);
    }
  } else {
    for (int g = 0; g < B; ++g) {
      k_blurWH<<<dim3(S, 1), dim3(S), 0, stream>>>(gt, pr, buf, (long long)g * S3, S3, W);
      k_blurD_ssim<<<dim3(S, 1, S / DCH), dim3(S), 0, stream>>>(buf, S3, acc, W);
    }
  }
  k_final<<<dim3(1), dim3(1), 0, stream>>>(acc, out);
}